// Round 2
// baseline (1565.850 us; speedup 1.0000x reference)
//
#include <hip/hip_runtime.h>
#include <math.h>

// SNN: 5 LIF layers, B=2048, dims 100->128->256->512->1024->784, 25 steps.
// Round 9: two fixes to the per-layer kernels, driven by rocprof on L5
// (608us, FETCH=782MB vs 105MB of A, MfmaUtil 12%, nothing saturated):
//  (a) XCD-aware tile mapping: m-tile = lb&31, n-tile = lb>>5. All n-tile
//      blocks sharing an m-tile's A rows now land on the SAME XCD (32%8==0),
//      so A is served from that XCD's private L2 instead of being re-fetched
//      from HBM by every XCD (~8x amplification observed).
//  (b) Step-batching S=5: the GEMMs of different timesteps are independent
//      (the LIF recurrence couples steps only at the epilogue), so each
//      K-sweep stages every B tile ONCE and runs 5 steps of MFMA against it
//      (80 MFMA/tile instead of 16), with 5 accumulator sets in registers
//      and the 5 LIF epilogues run in order afterwards. 5x compute per
//      staged tile (latency actually hidden), 5x less B staging traffic.
// Numerics bit-identical to round 8 (same per-element K-order / op chain).

typedef _Float16 f16;
typedef __attribute__((ext_vector_type(8))) short short8;
typedef __attribute__((ext_vector_type(8))) _Float16 half8;
typedef __attribute__((ext_vector_type(4))) _Float16 half4;
typedef __attribute__((ext_vector_type(4))) float f32x4;

#define B_TOTAL 2048
#define LO_SCALE 2.44140625e-4f  // 2^-12, undoes the lo x2^12 storage scale
#define ACC_SCALE 0.015625f      // 2^-6, undoes the x64 weight pre-scale
#define TILE_F16 8192            // one K-64 tile: 128 rows x 64 f16 = 16 KB

// ---------- fp32 64x64 GEMM + relu (layer-1 current, runs once) ------------
__global__ __launch_bounds__(256) void gemm_relu_f32_kernel(
    const float* __restrict__ h, const float* __restrict__ W,
    const float* __restrict__ bias, float* __restrict__ out, int N, int K) {
  __shared__ float As[16][64];
  __shared__ float Bs[16][64];

  const int t = threadIdx.x;
  const int tx = t & 15;
  const int ty = t >> 4;
  const int m0 = blockIdx.y * 64;
  const int n0 = blockIdx.x * 64;
  const int lr = t >> 2;
  const int lc = (t & 3) * 4;

  float acc[4][4];
#pragma unroll
  for (int i = 0; i < 4; ++i)
#pragma unroll
    for (int j = 0; j < 4; ++j) acc[i][j] = 0.0f;

  const int ktiles = (K + 15) / 16;
  for (int kt = 0; kt < ktiles; ++kt) {
    const int kbase = kt * 16;
    {
      const float* src = h + (size_t)(m0 + lr) * K + kbase + lc;
#pragma unroll
      for (int j = 0; j < 4; ++j) {
        const int kg = kbase + lc + j;
        As[lc + j][lr] = (kg < K) ? src[j] : 0.0f;
      }
    }
    {
      const int nr = n0 + lr;
      const float* src = W + (size_t)nr * K + kbase + lc;
#pragma unroll
      for (int j = 0; j < 4; ++j) {
        const int kg = kbase + lc + j;
        Bs[lc + j][lr] = (nr < N && kg < K) ? src[j] : 0.0f;
      }
    }
    __syncthreads();
#pragma unroll
    for (int k = 0; k < 16; ++k) {
      float a[4], bb[4];
#pragma unroll
      for (int i = 0; i < 4; ++i) a[i] = As[k][ty * 4 + i];
#pragma unroll
      for (int j = 0; j < 4; ++j) bb[j] = Bs[k][tx * 4 + j];
#pragma unroll
      for (int i = 0; i < 4; ++i)
#pragma unroll
        for (int j = 0; j < 4; ++j) acc[i][j] = fmaf(a[i], bb[j], acc[i][j]);
    }
    __syncthreads();
  }

#pragma unroll
  for (int i = 0; i < 4; ++i) {
    const int m = m0 + ty * 4 + i;
#pragma unroll
    for (int j = 0; j < 4; ++j) {
      const int n = n0 + tx * 4 + j;
      if (n < N) {
        float cur = acc[i][j] + bias[n];
        out[(size_t)m * N + n] = cur > 0.0f ? cur : 0.0f;
      }
    }
  }
}

// ---------- f16 2-split: W fp32 [N,K] -> Wc f16 [N, 2K] = [hi | lo*2^12] ---
__global__ __launch_bounds__(256) void split2_kernel(
    const float* __restrict__ W, f16* __restrict__ Wc, int total, int K) {
  const int idx = blockIdx.x * 256 + threadIdx.x;
  if (idx < total) {
    const int n = idx / K;
    const int k = idx - n * K;
    const float w64 = W[idx] * 64.0f;
    const f16 hi = (f16)w64;
    const float r = w64 - (float)hi;
    const f16 lo = (f16)(r * 4096.0f);
    const size_t base = (size_t)n * 2 * K + k;
    Wc[base] = hi;
    Wc[base + K] = lo;
  }
}

// ---------- lif1: full 25-step recurrence, cur1 is step-invariant ----------
__global__ __launch_bounds__(256) void lif1_kernel(
    const float* __restrict__ cur1, f16* __restrict__ s1_all) {
  const int i0 = (blockIdx.x * 256 + (int)threadIdx.x) * 4;
  const float4 c = *(const float4*)(cur1 + i0);
  const float ca[4] = {c.x, c.y, c.z, c.w};
  float m[4] = {0.0f, 0.0f, 0.0f, 0.0f};
  for (int st = 0; st < 25; ++st) {
    half4 sv;
#pragma unroll
    for (int j = 0; j < 4; ++j) {
      const float mo = m[j];
      const float reset = (mo - 1.0f > 0.0f) ? 1.0f : 0.0f;
      float mn = __fmul_rn(0.95f, mo);
      mn = __fadd_rn(mn, ca[j]);
      mn = __fsub_rn(mn, reset);
      m[j] = mn;
      sv[j] = (f16)((mn - 1.0f > 0.0f) ? 1.0f : 0.0f);
    }
    *(half4*)(s1_all + (size_t)st * (B_TOTAL * 128) + i0) = sv;
  }
}

// ---------- per-layer GEMM + LIF, 25 steps, batched 5 steps per K-sweep ----
// Block tile 64x64, 4 waves (2m x 2n), wave tile 32x32 via 16x16x32 MFMA,
// dual hi/lo accumulators x 5 steps. mem state in registers for all 25 steps.
// XCD-aware mapping: m-tile = lb&31 (A-row sharers colocate on one XCD).
// LDS: unpadded swizzled K-64 tiles (128 rows = 64 hi + 64 lo, 64 f16 cols).
//   K<=256: all K/64 tiles staged once; loop is barrier-free.
//   K>256:  2-tile double buffer, async-stage split, 1 barrier per K-tile.
__global__ __launch_bounds__(256) void layer_kernel(
    const f16* __restrict__ A_all,   // [25][2048][K] input spikes
    const f16* __restrict__ Wc,      // [N][2K] = [hi | lo]
    const float* __restrict__ bias,
    f16* __restrict__ spk_out,       // [25][2048][N]   (mode 0)
    float* __restrict__ sr, float* __restrict__ mr,  // [25][2048][N] (mode 1)
    int N, int K, int mode) {
  extern __shared__ f16 Bsm[];

  const int t = threadIdx.x;
  const int lane = t & 63;
  const int w = t >> 6;
  const int wm = w >> 1;
  const int wn = w & 1;
  const int lb = blockIdx.x;
  const int m0 = (lb & 31) * 64;   // 32%8==0 -> XCD = (m-tile)%8
  const int n0 = (lb >> 5) * 64;
  const int lrow = t >> 3;      // 0..31 (staging row within half-tile)
  const int lk = (t & 7) * 8;   // staging f16 col chunk
  const int K2 = 2 * K;
  const int nk = K >> 6;        // number of K-64 tiles

  // bias per owned column
  float bias_r[2];
#pragma unroll
  for (int j = 0; j < 2; ++j) {
    const int n = n0 + wn * 32 + j * 16 + (lane & 15);
    bias_r[j] = (n < N) ? bias[n] : 0.0f;
  }

  // 5 step-batched accumulator sets + membrane state (all registers)
  f32x4 acch[5][2][2], accl[5][2][2], memr[2][2];
#pragma unroll
  for (int i = 0; i < 2; ++i)
#pragma unroll
    for (int j = 0; j < 2; ++j) memr[i][j] = 0.0f;

  auto zacc = [&]() {
#pragma unroll
    for (int s = 0; s < 5; ++s)
#pragma unroll
      for (int i = 0; i < 2; ++i)
#pragma unroll
        for (int j = 0; j < 2; ++j) {
          acch[s][i][j] = 0.0f;
          accl[s][i][j] = 0.0f;
        }
  };

  const size_t Astep = (size_t)B_TOTAL * K;

  // stage K-64 tile kt into LDS tile q (global -> reg -> swizzled ds_write)
  auto stage = [&](int kt, int q) {
    f16* T = Bsm + q * TILE_F16;
#pragma unroll
    for (int i = 0; i < 2; ++i) {
      const int r = lrow + 32 * i;
      const int nr = n0 + r;
      short8 vh = {}, vl = {};
      if (nr < N) {
        const f16* src = Wc + (size_t)nr * K2 + kt * 64 + lk;
        vh = *(const short8*)(src);
        vl = *(const short8*)(src + K);
      }
      const int sw = lk ^ ((r & 7) << 3);
      *(short8*)(T + r * 64 + sw) = vh;
      *(short8*)(T + (64 + r) * 64 + sw) = vl;
    }
  };

  // one K-64 tile x 5 steps of MFMA; Abase includes row/lane/kt offsets
  auto compute_batch = [&](const f16* Abase, int q) {
    const f16* T = Bsm + q * TILE_F16;
#pragma unroll
    for (int ks = 0; ks < 64; ks += 32) {
      const int kb = ks + (lane >> 4) * 8;
      half8 bh[2], bl[2];
#pragma unroll
      for (int j = 0; j < 2; ++j) {
        const int rr = wn * 32 + j * 16 + (lane & 15);
        const int sw = kb ^ ((rr & 7) << 3);
        bh[j] = *(const half8*)(T + rr * 64 + sw);
        bl[j] = *(const half8*)(T + (64 + rr) * 64 + sw);
      }
#pragma unroll
      for (int s = 0; s < 5; ++s) {
        half8 af[2];
#pragma unroll
        for (int i = 0; i < 2; ++i)
          af[i] = *(const half8*)(Abase + (size_t)s * Astep +
                                  (size_t)i * 16 * K + ks);
#pragma unroll
        for (int i = 0; i < 2; ++i)
#pragma unroll
          for (int j = 0; j < 2; ++j) {
            acch[s][i][j] = __builtin_amdgcn_mfma_f32_16x16x32_f16(
                af[i], bh[j], acch[s][i][j], 0, 0, 0);
            accl[s][i][j] = __builtin_amdgcn_mfma_f32_16x16x32_f16(
                af[i], bl[j], accl[s][i][j], 0, 0, 0);
          }
      }
    }
  };

  // epilogue for steps st0..st0+4: combine hi/lo, bias+relu, LIF, store
  auto epilogue5 = [&](int st0) {
    const int col = lane & 15;
    const int rbase = (lane >> 4) * 4;
#pragma unroll
    for (int s = 0; s < 5; ++s) {
      const int st = st0 + s;
#pragma unroll
      for (int i = 0; i < 2; ++i) {
#pragma unroll
        for (int r = 0; r < 4; ++r) {
          const int m = m0 + wm * 32 + i * 16 + rbase + r;
#pragma unroll
          for (int j = 0; j < 2; ++j) {
            const int n = n0 + wn * 32 + j * 16 + col;
            if (n < N) {
              const float v = __fadd_rn(acch[s][i][j][r],
                                        __fmul_rn(accl[s][i][j][r], LO_SCALE));
              float cur = __fadd_rn(__fmul_rn(v, ACC_SCALE), bias_r[j]);
              cur = cur > 0.0f ? cur : 0.0f;
              const float mo = memr[i][j][r];
              const float reset = (mo - 1.0f > 0.0f) ? 1.0f : 0.0f;
              float mn = __fmul_rn(0.95f, mo);
              mn = __fadd_rn(mn, cur);
              mn = __fsub_rn(mn, reset);
              memr[i][j][r] = mn;
              const float sp = (mn - 1.0f > 0.0f) ? 1.0f : 0.0f;
              const size_t idx = (size_t)st * (B_TOTAL * (size_t)N) +
                                 (size_t)m * N + n;
              if (mode == 1) {
                sr[idx] = sp;
                mr[idx] = tanhf(mn);
              } else {
                spk_out[idx] = (f16)sp;
              }
            }
          }
        }
      }
    }
  };

  const f16* Acur = A_all + (size_t)(m0 + wm * 32 + (lane & 15)) * K +
                    ((lane >> 4) * 8);

  if (nk <= 4) {
    // ---- resident-B path (L2: nk=2, L3: nk=4): stage once, no barriers ----
    for (int kt = 0; kt < nk; ++kt) stage(kt, kt);
    __syncthreads();
    for (int b = 0; b < 5; ++b) {
      zacc();
      for (int kt = 0; kt < nk; ++kt) compute_batch(Acur + kt * 64, kt);
      epilogue5(b * 5);
      Acur += 5 * Astep;
    }
  } else {
    // ---- double-buffer path (L4: nk=8, L5: nk=16) ----
    stage(0, 0);
    __syncthreads();
    zacc();
    int kt = 0, st0 = 0;
    const int total = 5 * nk;
    for (int it = 0; it < total; ++it) {
      const int ktn = (kt + 1 == nk) ? 0 : kt + 1;
      const bool do_stage = (it + 1 < total);
      // issue next tile's global loads EARLY (latency hides under 80 MFMA)
      short8 vh[2], vl[2];
      if (do_stage) {
#pragma unroll
        for (int i = 0; i < 2; ++i) {
          const int r = lrow + 32 * i;
          const int nr = n0 + r;
          vh[i] = {};
          vl[i] = {};
          if (nr < N) {
            const f16* src = Wc + (size_t)nr * K2 + ktn * 64 + lk;
            vh[i] = *(const short8*)(src);
            vl[i] = *(const short8*)(src + K);
          }
        }
      }
      compute_batch(Acur + kt * 64, it & 1);
      if (do_stage) {
        f16* T = Bsm + ((it + 1) & 1) * TILE_F16;
#pragma unroll
        for (int i = 0; i < 2; ++i) {
          const int r = lrow + 32 * i;
          const int sw = lk ^ ((r & 7) << 3);
          *(short8*)(T + r * 64 + sw) = vh[i];
          *(short8*)(T + (64 + r) * 64 + sw) = vl[i];
        }
      }
      __syncthreads();
      if (++kt == nk) {
        kt = 0;
        epilogue5(st0);
        zacc();
        st0 += 5;
        Acur += 5 * Astep;
      }
    }
  }
}

// ---------------------------------------------------------------------------
extern "C" void kernel_launch(void* const* d_in, const int* in_sizes, int n_in,
                              void* d_out, int out_size, void* d_ws,
                              size_t ws_size, hipStream_t stream) {
  const float* x = (const float*)d_in[0];
  const float* W[5];
  const float* bi[5];
  for (int i = 0; i < 5; ++i) {
    W[i] = (const float*)d_in[1 + 2 * i];
    bi[i] = (const float*)d_in[2 + 2 * i];
  }

  const int B = B_TOTAL;
  const int Ns[5] = {128, 256, 512, 1024, 784};
  const int Ks[5] = {100, 128, 256, 512, 1024};

  char* ws = (char*)d_ws;
  size_t off = 0;
  auto alloc = [&](size_t bytes) {
    void* p = ws + off;
    off = (off + bytes + 255) & ~(size_t)255;
    return p;
  };

  float* cur1 = (float*)alloc((size_t)B * 128 * 4);
  // all-step spike buffers: s{l}[25][B][N_l] f16
  f16* s1 = (f16*)alloc((size_t)25 * B * 128 * 2);
  f16* s2 = (f16*)alloc((size_t)25 * B * 256 * 2);
  f16* s3 = (f16*)alloc((size_t)25 * B * 512 * 2);
  f16* s4 = (f16*)alloc((size_t)25 * B * 1024 * 2);
  f16* Wc[5];
  for (int i = 1; i < 5; ++i)
    Wc[i] = (f16*)alloc((size_t)Ns[i] * Ks[i] * 2 * 2);

  float* outF = (float*)d_out;
  float* spk_rec = outF;
  float* mem_rec = outF + (size_t)25 * B * 784;

  // 2-split weights for layers 2..5
  for (int i = 1; i < 5; ++i) {
    const int total = Ns[i] * Ks[i];
    split2_kernel<<<(total + 255) / 256, 256, 0, stream>>>(W[i], Wc[i], total,
                                                           Ks[i]);
  }

  // layer-1 current: relu(x @ W1^T + b1), computed once (x is step-invariant)
  gemm_relu_f32_kernel<<<dim3(2, B / 64), 256, 0, stream>>>(x, W[0], bi[0],
                                                            cur1, 128, 100);

  // layer-1 LIF: full 25-step recurrence (cur1 fixed, mem in registers)
  lif1_kernel<<<(B * 128) / 1024, 256, 0, stream>>>(cur1, s1);

  // layers 2..5: one kernel each, 25 steps internal, mem in registers.
  // grid = 32 m-tiles x nbx n-tiles; kernel derives both from lb.
  const size_t TB = (size_t)TILE_F16 * 2;  // 16 KB per K-64 tile
  layer_kernel<<<32 * 4, 256, 2 * TB, stream>>>(
      s1, Wc[1], bi[1], s2, nullptr, nullptr, 256, 128, 0);
  layer_kernel<<<32 * 8, 256, 4 * TB, stream>>>(
      s2, Wc[2], bi[2], s3, nullptr, nullptr, 512, 256, 0);
  layer_kernel<<<32 * 16, 256, 2 * TB, stream>>>(
      s3, Wc[3], bi[3], s4, nullptr, nullptr, 1024, 512, 0);
  layer_kernel<<<32 * 13, 256, 2 * TB, stream>>>(
      s4, Wc[4], bi[4], nullptr, spk_rec, mem_rec, 784, 1024, 1);
}

// Round 3
// 1349.342 us; speedup vs baseline: 1.1605x; 1.1605x over previous
//
#include <hip/hip_runtime.h>
#include <math.h>

// SNN: 5 LIF layers, B=2048, dims 100->128->256->512->1024->784, 25 steps.
// Round 10: revert to the round-8 structure (known 1391us; round-9's
// S=5 batching pushed acc regs to ~176 VGPR and regressed) and apply ONLY
// the XCD-aware tile mapping. Round-8 rocprof: L5 = 608us, FETCH = 782MB
// vs a 105MB A panel -> ~7.5x HBM amplification because the 13 n-blocks
// sharing an m-tile's A rows were scattered across all 8 XCDs (XCD=lb%8).
// New mapping m-tile = lb&31, n-tile = lb>>5 (32%8==0) puts all A-sharers
// of an m-tile on XCD m%8: A slice becomes L2-resident on one XCD, and the
// direct-from-global A-fragment loads feeding MFMA turn from ~900-cyc HBM
// misses into ~200-cyc L2 hits (we are latency-bound: HBM 23%, Mfma 12%).
// Numerics bit-identical to round 8.

typedef _Float16 f16;
typedef __attribute__((ext_vector_type(8))) short short8;
typedef __attribute__((ext_vector_type(8))) _Float16 half8;
typedef __attribute__((ext_vector_type(4))) _Float16 half4;
typedef __attribute__((ext_vector_type(4))) float f32x4;

#define B_TOTAL 2048
#define LO_SCALE 2.44140625e-4f  // 2^-12, undoes the lo x2^12 storage scale
#define ACC_SCALE 0.015625f      // 2^-6, undoes the x64 weight pre-scale
#define TILE_F16 8192            // one K-64 tile: 128 rows x 64 f16 = 16 KB

// ---------- fp32 64x64 GEMM + relu (layer-1 current, runs once) ------------
__global__ __launch_bounds__(256) void gemm_relu_f32_kernel(
    const float* __restrict__ h, const float* __restrict__ W,
    const float* __restrict__ bias, float* __restrict__ out, int N, int K) {
  __shared__ float As[16][64];
  __shared__ float Bs[16][64];

  const int t = threadIdx.x;
  const int tx = t & 15;
  const int ty = t >> 4;
  const int m0 = blockIdx.y * 64;
  const int n0 = blockIdx.x * 64;
  const int lr = t >> 2;
  const int lc = (t & 3) * 4;

  float acc[4][4];
#pragma unroll
  for (int i = 0; i < 4; ++i)
#pragma unroll
    for (int j = 0; j < 4; ++j) acc[i][j] = 0.0f;

  const int ktiles = (K + 15) / 16;
  for (int kt = 0; kt < ktiles; ++kt) {
    const int kbase = kt * 16;
    {
      const float* src = h + (size_t)(m0 + lr) * K + kbase + lc;
#pragma unroll
      for (int j = 0; j < 4; ++j) {
        const int kg = kbase + lc + j;
        As[lc + j][lr] = (kg < K) ? src[j] : 0.0f;
      }
    }
    {
      const int nr = n0 + lr;
      const float* src = W + (size_t)nr * K + kbase + lc;
#pragma unroll
      for (int j = 0; j < 4; ++j) {
        const int kg = kbase + lc + j;
        Bs[lc + j][lr] = (nr < N && kg < K) ? src[j] : 0.0f;
      }
    }
    __syncthreads();
#pragma unroll
    for (int k = 0; k < 16; ++k) {
      float a[4], bb[4];
#pragma unroll
      for (int i = 0; i < 4; ++i) a[i] = As[k][ty * 4 + i];
#pragma unroll
      for (int j = 0; j < 4; ++j) bb[j] = Bs[k][tx * 4 + j];
#pragma unroll
      for (int i = 0; i < 4; ++i)
#pragma unroll
        for (int j = 0; j < 4; ++j) acc[i][j] = fmaf(a[i], bb[j], acc[i][j]);
    }
    __syncthreads();
  }

#pragma unroll
  for (int i = 0; i < 4; ++i) {
    const int m = m0 + ty * 4 + i;
#pragma unroll
    for (int j = 0; j < 4; ++j) {
      const int n = n0 + tx * 4 + j;
      if (n < N) {
        float cur = acc[i][j] + bias[n];
        out[(size_t)m * N + n] = cur > 0.0f ? cur : 0.0f;
      }
    }
  }
}

// ---------- f16 2-split: W fp32 [N,K] -> Wc f16 [N, 2K] = [hi | lo*2^12] ---
__global__ __launch_bounds__(256) void split2_kernel(
    const float* __restrict__ W, f16* __restrict__ Wc, int total, int K) {
  const int idx = blockIdx.x * 256 + threadIdx.x;
  if (idx < total) {
    const int n = idx / K;
    const int k = idx - n * K;
    const float w64 = W[idx] * 64.0f;
    const f16 hi = (f16)w64;
    const float r = w64 - (float)hi;
    const f16 lo = (f16)(r * 4096.0f);
    const size_t base = (size_t)n * 2 * K + k;
    Wc[base] = hi;
    Wc[base + K] = lo;
  }
}

// ---------- lif1: full 25-step recurrence, cur1 is step-invariant ----------
__global__ __launch_bounds__(256) void lif1_kernel(
    const float* __restrict__ cur1, f16* __restrict__ s1_all) {
  const int i0 = (blockIdx.x * 256 + (int)threadIdx.x) * 4;
  const float4 c = *(const float4*)(cur1 + i0);
  const float ca[4] = {c.x, c.y, c.z, c.w};
  float m[4] = {0.0f, 0.0f, 0.0f, 0.0f};
  for (int st = 0; st < 25; ++st) {
    half4 sv;
#pragma unroll
    for (int j = 0; j < 4; ++j) {
      const float mo = m[j];
      const float reset = (mo - 1.0f > 0.0f) ? 1.0f : 0.0f;
      float mn = __fmul_rn(0.95f, mo);
      mn = __fadd_rn(mn, ca[j]);
      mn = __fsub_rn(mn, reset);
      m[j] = mn;
      sv[j] = (f16)((mn - 1.0f > 0.0f) ? 1.0f : 0.0f);
    }
    *(half4*)(s1_all + (size_t)st * (B_TOTAL * 128) + i0) = sv;
  }
}

// ---------- per-layer GEMM + LIF over all 25 steps -------------------------
// Block tile 64x64, 4 waves (2m x 2n), wave tile 32x32 via 16x16x32 MFMA,
// dual hi/lo accumulators. mem state lives in registers for all 25 steps.
// XCD-aware mapping: m-tile = lb&31, n-tile = lb>>5 (32%8==0 -> all blocks
// sharing an m-tile's A rows land on XCD m%8; A slice L2-resident there).
// LDS: unpadded swizzled K-64 tiles (128 rows = 64 hi + 64 lo, 64 f16 cols).
//   K<=256: all K/64 tiles staged once, 25-step loop is barrier-free.
//   K>256:  2-tile double buffer, async-stage split, 1 barrier per K-tile.
__global__ __launch_bounds__(256) void layer_kernel(
    const f16* __restrict__ A_all,   // [25][2048][K] input spikes
    const f16* __restrict__ Wc,      // [N][2K] = [hi | lo]
    const float* __restrict__ bias,
    f16* __restrict__ spk_out,       // [25][2048][N]   (mode 0)
    float* __restrict__ sr, float* __restrict__ mr,  // [25][2048][N] (mode 1)
    int N, int K, int mode) {
  extern __shared__ f16 Bsm[];

  const int t = threadIdx.x;
  const int lane = t & 63;
  const int w = t >> 6;
  const int wm = w >> 1;
  const int wn = w & 1;
  const int lb = blockIdx.x;
  const int m0 = (lb & 31) * 64;   // XCD = lb%8 = m-tile%8
  const int n0 = (lb >> 5) * 64;
  const int lrow = t >> 3;      // 0..31 (staging row within half-tile)
  const int lk = (t & 7) * 8;   // staging f16 col chunk
  const int K2 = 2 * K;
  const int nk = K >> 6;        // number of K-64 tiles

  // bias per owned column
  float bias_r[2];
#pragma unroll
  for (int j = 0; j < 2; ++j) {
    const int n = n0 + wn * 32 + j * 16 + (lane & 15);
    bias_r[j] = (n < N) ? bias[n] : 0.0f;
  }

  // accumulators + membrane state (registers, persistent across 25 steps)
  f32x4 acch[2][2], accl[2][2], memr[2][2];
#pragma unroll
  for (int i = 0; i < 2; ++i)
#pragma unroll
    for (int j = 0; j < 2; ++j) memr[i][j] = 0.0f;

  auto zacc = [&]() {
#pragma unroll
    for (int i = 0; i < 2; ++i)
#pragma unroll
      for (int j = 0; j < 2; ++j) {
        acch[i][j] = 0.0f;
        accl[i][j] = 0.0f;
      }
  };

  // stage K-64 tile kt into LDS tile q (global -> reg -> swizzled ds_write)
  auto stage = [&](int kt, int q) {
    f16* T = Bsm + q * TILE_F16;
#pragma unroll
    for (int i = 0; i < 2; ++i) {
      const int r = lrow + 32 * i;
      const int nr = n0 + r;
      short8 vh = {}, vl = {};
      if (nr < N) {
        const f16* src = Wc + (size_t)nr * K2 + kt * 64 + lk;
        vh = *(const short8*)(src);
        vl = *(const short8*)(src + K);
      }
      const int sw = lk ^ ((r & 7) << 3);
      *(short8*)(T + r * 64 + sw) = vh;
      *(short8*)(T + (64 + r) * 64 + sw) = vl;
    }
  };

  // one K-64 tile of MFMA; At already includes row/lane/kt offsets
  auto compute = [&](const f16* At, int q) {
    const f16* T = Bsm + q * TILE_F16;
#pragma unroll
    for (int ks = 0; ks < 64; ks += 32) {
      const int kb = ks + (lane >> 4) * 8;
      half8 af[2], bh[2], bl[2];
#pragma unroll
      for (int i = 0; i < 2; ++i)
        af[i] = *(const half8*)(At + (size_t)i * 16 * K + ks);
#pragma unroll
      for (int j = 0; j < 2; ++j) {
        const int rr = wn * 32 + j * 16 + (lane & 15);
        const int sw = kb ^ ((rr & 7) << 3);
        bh[j] = *(const half8*)(T + rr * 64 + sw);
        bl[j] = *(const half8*)(T + (64 + rr) * 64 + sw);
      }
#pragma unroll
      for (int i = 0; i < 2; ++i)
#pragma unroll
        for (int j = 0; j < 2; ++j) {
          acch[i][j] = __builtin_amdgcn_mfma_f32_16x16x32_f16(
              af[i], bh[j], acch[i][j], 0, 0, 0);
          accl[i][j] = __builtin_amdgcn_mfma_f32_16x16x32_f16(
              af[i], bl[j], accl[i][j], 0, 0, 0);
        }
    }
  };

  // epilogue for step st: combine hi/lo, bias+relu, LIF update, store
  auto epilogue = [&](int st) {
    const int col = lane & 15;
    const int rbase = (lane >> 4) * 4;
#pragma unroll
    for (int i = 0; i < 2; ++i) {
#pragma unroll
      for (int r = 0; r < 4; ++r) {
        const int m = m0 + wm * 32 + i * 16 + rbase + r;
#pragma unroll
        for (int j = 0; j < 2; ++j) {
          const int n = n0 + wn * 32 + j * 16 + col;
          if (n < N) {
            const float v =
                __fadd_rn(acch[i][j][r], __fmul_rn(accl[i][j][r], LO_SCALE));
            float cur = __fadd_rn(__fmul_rn(v, ACC_SCALE), bias_r[j]);
            cur = cur > 0.0f ? cur : 0.0f;
            const float mo = memr[i][j][r];
            const float reset = (mo - 1.0f > 0.0f) ? 1.0f : 0.0f;
            float mn = __fmul_rn(0.95f, mo);
            mn = __fadd_rn(mn, cur);
            mn = __fsub_rn(mn, reset);
            memr[i][j][r] = mn;
            const float s = (mn - 1.0f > 0.0f) ? 1.0f : 0.0f;
            const size_t idx = (size_t)st * (B_TOTAL * (size_t)N) +
                               (size_t)m * N + n;
            if (mode == 1) {
              sr[idx] = s;
              mr[idx] = tanhf(mn);
            } else {
              spk_out[idx] = (f16)s;
            }
          }
        }
      }
    }
  };

  const f16* Acur = A_all + (size_t)(m0 + wm * 32 + (lane & 15)) * K +
                    ((lane >> 4) * 8);
  const size_t Astep = (size_t)B_TOTAL * K;

  if (nk <= 4) {
    // ---- resident-B path (L2: nk=2, L3: nk=4): stage once, no barriers ----
    for (int kt = 0; kt < nk; ++kt) stage(kt, kt);
    __syncthreads();
    for (int st = 0; st < 25; ++st) {
      zacc();
      for (int kt = 0; kt < nk; ++kt) compute(Acur + kt * 64, kt);
      epilogue(st);
      Acur += Astep;
    }
  } else {
    // ---- double-buffer path (L4: nk=8, L5: nk=16) ----
    stage(0, 0);
    __syncthreads();
    zacc();
    int kt = 0, st = 0;
    const int total = 25 * nk;
    for (int it = 0; it < total; ++it) {
      const int ktn = (kt + 1 == nk) ? 0 : kt + 1;
      const bool do_stage = (it + 1 < total);
      // issue next tile's global loads EARLY (latency hides under MFMA)
      short8 vh[2], vl[2];
      if (do_stage) {
#pragma unroll
        for (int i = 0; i < 2; ++i) {
          const int r = lrow + 32 * i;
          const int nr = n0 + r;
          vh[i] = {};
          vl[i] = {};
          if (nr < N) {
            const f16* src = Wc + (size_t)nr * K2 + ktn * 64 + lk;
            vh[i] = *(const short8*)(src);
            vl[i] = *(const short8*)(src + K);
          }
        }
      }
      compute(Acur + kt * 64, it & 1);
      if (do_stage) {
        f16* T = Bsm + ((it + 1) & 1) * TILE_F16;
#pragma unroll
        for (int i = 0; i < 2; ++i) {
          const int r = lrow + 32 * i;
          const int sw = lk ^ ((r & 7) << 3);
          *(short8*)(T + r * 64 + sw) = vh[i];
          *(short8*)(T + (64 + r) * 64 + sw) = vl[i];
        }
      }
      __syncthreads();
      if (++kt == nk) {
        kt = 0;
        epilogue(st);
        zacc();
        ++st;
        Acur += Astep;
      }
    }
  }
}

// ---------------------------------------------------------------------------
extern "C" void kernel_launch(void* const* d_in, const int* in_sizes, int n_in,
                              void* d_out, int out_size, void* d_ws,
                              size_t ws_size, hipStream_t stream) {
  const float* x = (const float*)d_in[0];
  const float* W[5];
  const float* bi[5];
  for (int i = 0; i < 5; ++i) {
    W[i] = (const float*)d_in[1 + 2 * i];
    bi[i] = (const float*)d_in[2 + 2 * i];
  }

  const int B = B_TOTAL;
  const int Ns[5] = {128, 256, 512, 1024, 784};
  const int Ks[5] = {100, 128, 256, 512, 1024};

  char* ws = (char*)d_ws;
  size_t off = 0;
  auto alloc = [&](size_t bytes) {
    void* p = ws + off;
    off = (off + bytes + 255) & ~(size_t)255;
    return p;
  };

  float* cur1 = (float*)alloc((size_t)B * 128 * 4);
  // all-step spike buffers: s{l}[25][B][N_l] f16
  f16* s1 = (f16*)alloc((size_t)25 * B * 128 * 2);
  f16* s2 = (f16*)alloc((size_t)25 * B * 256 * 2);
  f16* s3 = (f16*)alloc((size_t)25 * B * 512 * 2);
  f16* s4 = (f16*)alloc((size_t)25 * B * 1024 * 2);
  f16* Wc[5];
  for (int i = 1; i < 5; ++i)
    Wc[i] = (f16*)alloc((size_t)Ns[i] * Ks[i] * 2 * 2);

  float* outF = (float*)d_out;
  float* spk_rec = outF;
  float* mem_rec = outF + (size_t)25 * B * 784;

  // 2-split weights for layers 2..5
  for (int i = 1; i < 5; ++i) {
    const int total = Ns[i] * Ks[i];
    split2_kernel<<<(total + 255) / 256, 256, 0, stream>>>(W[i], Wc[i], total,
                                                           Ks[i]);
  }

  // layer-1 current: relu(x @ W1^T + b1), computed once (x is step-invariant)
  gemm_relu_f32_kernel<<<dim3(2, B / 64), 256, 0, stream>>>(x, W[0], bi[0],
                                                            cur1, 128, 100);

  // layer-1 LIF: full 25-step recurrence (cur1 fixed, mem in registers)
  lif1_kernel<<<(B * 128) / 1024, 256, 0, stream>>>(cur1, s1);

  // layers 2..5: one kernel each, 25 steps internal, mem in registers.
  // grid = 32 m-tiles x nbx n-tiles; kernel derives (m,n) from lb bits.
  const size_t TB = (size_t)TILE_F16 * 2;  // 16 KB per K-64 tile
  layer_kernel<<<32 * 4, 256, 2 * TB, stream>>>(
      s1, Wc[1], bi[1], s2, nullptr, nullptr, 256, 128, 0);
  layer_kernel<<<32 * 8, 256, 4 * TB, stream>>>(
      s2, Wc[2], bi[2], s3, nullptr, nullptr, 512, 256, 0);
  layer_kernel<<<32 * 16, 256, 2 * TB, stream>>>(
      s3, Wc[3], bi[3], s4, nullptr, nullptr, 1024, 512, 0);
  layer_kernel<<<32 * 13, 256, 2 * TB, stream>>>(
      s4, Wc[4], bi[4], nullptr, spk_rec, mem_rec, 784, 1024, 1);
}